// Round 13
// baseline (6648.080 us; speedup 1.0000x reference)
//
#include <hip/hip_runtime.h>
#include <cstdint>
#include <cstddef>

#define BB 2
#define NN 16384
#define SS 4096
#define KK 32
#define FIN 16
#define R2C 0.01f
#define NCHUNK 256   // chunks = 64-slot ranges of the Morton-cell-sorted point array

typedef unsigned long long u64;

// ---------------- DPP wave reductions (result valid at lane 63) ----------------
// update_dpp(old=own, src=own): invalid lanes keep own value -> idempotent.
template <int CTRL>
__device__ __forceinline__ float fstep(float v) {
  const int nv = __builtin_amdgcn_update_dpp(__float_as_int(v), __float_as_int(v),
                                             CTRL, 0xf, 0xf, false);
  return fmaxf(v, __int_as_float(nv));
}
__device__ __forceinline__ float fchain(float v) {
  v = fstep<0x111>(v); v = fstep<0x112>(v); v = fstep<0x114>(v);
  v = fstep<0x118>(v); v = fstep<0x142>(v); v = fstep<0x143>(v);
  return v;  // lane 63 holds wave max
}
template <int CTRL>
__device__ __forceinline__ void fstep4(float& a, float& b, float& c, float& d) {
  a = fstep<CTRL>(a); b = fstep<CTRL>(b); c = fstep<CTRL>(c); d = fstep<CTRL>(d);
}
__device__ __forceinline__ void fchain4(float& a, float& b, float& c, float& d) {
  fstep4<0x111>(a, b, c, d); fstep4<0x112>(a, b, c, d); fstep4<0x114>(a, b, c, d);
  fstep4<0x118>(a, b, c, d); fstep4<0x142>(a, b, c, d); fstep4<0x143>(a, b, c, d);
}
template <int CTRL>
__device__ __forceinline__ void fstep2(float& a, float& b) {
  a = fstep<CTRL>(a); b = fstep<CTRL>(b);
}
__device__ __forceinline__ void fchain2(float& a, float& b) {
  fstep2<0x111>(a, b); fstep2<0x112>(a, b); fstep2<0x114>(a, b);
  fstep2<0x118>(a, b); fstep2<0x142>(a, b); fstep2<0x143>(a, b);
}
template <int CTRL>
__device__ __forceinline__ int istep(int v) {
  const int nv = __builtin_amdgcn_update_dpp(v, v, CTRL, 0xf, 0xf, false);
  return nv < v ? nv : v;
}
__device__ __forceinline__ int imin_wave(int v) {
  v = istep<0x111>(v); v = istep<0x112>(v); v = istep<0x114>(v);
  v = istep<0x118>(v); v = istep<0x142>(v); v = istep<0x143>(v);
  return v;  // lane 63 holds wave min
}
// f64-packed key chain for phase C (key = (dm_bits<<32)|~pid, positive double)
template <int CTRL>
__device__ __forceinline__ double kstep(double k) {
  const u64 kb = (u64)__double_as_longlong(k);
  const int lo = (int)(unsigned int)kb;
  const int hi = (int)(unsigned int)(kb >> 32);
  const int nlo = __builtin_amdgcn_update_dpp(lo, lo, CTRL, 0xf, 0xf, false);
  const int nhi = __builtin_amdgcn_update_dpp(hi, hi, CTRL, 0xf, 0xf, false);
  const double nk = __longlong_as_double(
      (long long)(((u64)(unsigned int)nhi << 32) | (unsigned int)nlo));
  return fmax(k, nk);
}
__device__ __forceinline__ double kchain(double k) {
  k = kstep<0x111>(k); k = kstep<0x112>(k); k = kstep<0x114>(k);
  k = kstep<0x118>(k); k = kstep<0x142>(k); k = kstep<0x143>(k);
  return k;
}

// ---------------- binning: counting-sort points into Morton-ordered cells ----------------
__device__ __forceinline__ int part3(int x) {  // 3 bits -> bits 0,3,6
  return (x & 1) | ((x & 2) << 2) | ((x & 4) << 4);
}

__global__ __launch_bounds__(512) void bin_kernel(const float* __restrict__ pos,
                                                  float4* __restrict__ cellpts,
                                                  float4* __restrict__ bboxLo,
                                                  float4* __restrict__ bboxHi) {
  const int b = blockIdx.x, t = threadIdx.x;
  const float* __restrict__ p = pos + (size_t)b * NN * 3;
  __shared__ int hist[512], sA[512], sB[512];
  hist[t] = 0;
  __syncthreads();
  int cidc[NN / 512];  // 32 per thread
#pragma unroll
  for (int m = 0; m < NN / 512; ++m) {
    const int i = m * 512 + t;
    const float x = p[i * 3 + 0], y = p[i * 3 + 1], z = p[i * 3 + 2];
    const int cx = min(7, (int)(x * 8.0f));
    const int cy = min(7, (int)(y * 8.0f));
    const int cz = min(7, (int)(z * 8.0f));
    const int cid = part3(cx) | (part3(cy) << 1) | (part3(cz) << 2);  // Morton
    cidc[m] = cid;
    atomicAdd(&hist[cid], 1);
  }
  __syncthreads();
  sA[t] = hist[t];
  __syncthreads();
  int* src = sA;
  int* dst = sB;
  for (int off = 1; off < 512; off <<= 1) {
    int v = src[t];
    if (t >= off) v += src[t - off];
    dst[t] = v;
    __syncthreads();
    int* tmp = src; src = dst; dst = tmp;
  }
  const int excl = (t == 0) ? 0 : src[t - 1];
  __syncthreads();
  hist[t] = excl;
  __syncthreads();
#pragma unroll
  for (int m = 0; m < NN / 512; ++m) {
    const int i = m * 512 + t;
    const int slot = atomicAdd(&hist[cidc[m]], 1);
    cellpts[(size_t)b * NN + slot] =
        make_float4(p[i * 3 + 0], p[i * 3 + 1], p[i * 3 + 2], __int_as_float(i));
  }
  __threadfence_block();
  __syncthreads();
  if (t < NCHUNK) {
    float4 lo = make_float4(1e30f, 1e30f, 1e30f, 0.0f);
    float4 hi = make_float4(-1e30f, -1e30f, -1e30f, 0.0f);
    for (int k = 0; k < 64; ++k) {
      const float4 q = cellpts[(size_t)b * NN + t * 64 + k];
      lo.x = fminf(lo.x, q.x); lo.y = fminf(lo.y, q.y); lo.z = fminf(lo.z, q.z);
      hi.x = fmaxf(hi.x, q.x); hi.y = fmaxf(hi.y, q.y); hi.z = fmaxf(hi.z, q.z);
    }
    bboxLo[b * NCHUNK + t] = lo;
    bboxHi[b * NCHUNK + t] = hi;
  }
}

// ---------------- FPS: one 512-thread block (8 waves) per batch ----------------
// Exact AABB-pruned FPS (bit-identical, proven r5-r11). r12/r13:
//  - B reduction: f32 DPP max chains (2-cyc v_max_f32, was 4-cyc f64) + exact
//    argmax via ballot/readlane; tie (rare, wave-uniform) -> imin_wave on pid
//  - branchless prefetch: chunk ids via select (junk slots -> chunk wid, loads
//    harmless), processing gated only by uniform rem counts
//  - per-chunk argmax COORDS in sCoord[256]; C matches winning key to a slot
//    and broadcast-reads the coords from LDS (~120 cyc, was ~220 s_load)
__global__ __launch_bounds__(512, 1) void fps_kernel(const float* __restrict__ pos,
                                                     const float4* __restrict__ cellpts,
                                                     const float4* __restrict__ bboxLo,
                                                     const float4* __restrict__ bboxHi,
                                                     int* __restrict__ idx_out) {
  const int b = blockIdx.x;
  const int t = threadIdx.x;
  const int wid = t >> 6;
  const int lane = t & 63;
  const float* __restrict__ p = pos + (size_t)b * NN * 3;
  const float4* __restrict__ cp = cellpts + (size_t)b * NN;

  __shared__ float sDmin[NN];       // 64 KB, indexed by sorted slot
  __shared__ u64 sKey[2][NCHUNK];   // double-buffered packed chunk maxima
  __shared__ float4 sCoord[NCHUNK]; // coords (+pid) of each chunk's argmax

  const int cown = ((lane & 31) << 3) | wid;  // owned chunk (real for lane<32)
  const int slotOwn = (wid << 5) | (lane & 31);
  const float4 blo = bboxLo[b * NCHUNK + cown];
  const float4 bhi = bboxHi[b * NCHUNK + cown];

  const u64 initKey = ((u64)(unsigned int)__float_as_int(1e30f) << 32) |
                      (unsigned int)(~0);
  if (t < NCHUNK) sKey[0][t] = initKey;
  for (int s = t; s < NN; s += 512) sDmin[s] = 1e10f;
  if (t == 0) idx_out[b * SS + 0] = 0;
  float lx = p[0], ly = p[1], lz = p[2];
  u64 kOwn = initKey;
  __syncthreads();

  int buf = 0;

  for (int it = 1; it < SS; ++it) {
    // ---- A: test owned chunks (pure VALU, boxes in regs) ----
    const float mvOwn = __int_as_float((int)(unsigned int)(kOwn >> 32));
    const float ax = fmaxf(fmaxf(blo.x - lx, lx - bhi.x), 0.0f);
    const float ay = fmaxf(fmaxf(blo.y - ly, ly - bhi.y), 0.0f);
    const float az = fmaxf(fmaxf(blo.z - lz, lz - bhi.z), 0.0f);
    const float bl2 = ax * ax + ay * ay + az * az;
    // skip iff conservative lower bound exceeds chunk max dmin: then
    // min(dmin_j, d_j) == dmin_j exactly for every member (bit-exact skip).
    const bool act = (lane < 32) && !(bl2 * 0.99999f > mvOwn);
    if ((lane < 32) && !act) sKey[buf ^ 1][slotOwn] = kOwn;  // carry (stride-1)
    unsigned int mm = (unsigned int)__ballot(act);
    int rem = (int)__popc(mm);  // wave-uniform

    // ---- B: quads, branchless 8-deep prefetch (junk slots load chunk wid) ----
    int ca0, ca1, ca2, ca3, cb0, cb1, cb2, cb3;
    float4 Pa0, Pa1, Pa2, Pa3, Pb0, Pb1, Pb2, Pb3;
    float oa0, oa1, oa2, oa3, ob0, ob1, ob2, ob3;
#define NEXTC(cX)                                         \
    {                                                     \
      const int l = mm ? (int)__builtin_ctz(mm) : 0;      \
      mm &= mm - 1;                                       \
      cX = (l << 3) | wid;                                \
    }
#define LOADC(cX, PX, oX)                                 \
    PX = cp[(size_t)((cX << 6) + lane)];                  \
    oX = sDmin[(cX << 6) + lane];
#define DIST(PX, oX, dmX)                                                        \
    float dmX;                                                                   \
    {                                                                            \
      const float dx = PX.x - lx, dy = PX.y - ly, dz = PX.z - lz;                \
      const float d = __fadd_rn(__fadd_rn(__fmul_rn(dx, dx), __fmul_rn(dy, dy)), \
                                __fmul_rn(dz, dz));                              \
      dmX = fminf(oX, d);                                                        \
    }
    // exact per-chunk (max dmin, lowest-pid argmax); V computed by f32 chain
#define CHFIN(cX, dmX, VX, PX)                                                   \
    {                                                                            \
      const int sVb = __builtin_amdgcn_readlane(__float_as_int(VX), 63);         \
      const float sV = __int_as_float(sVb);                                      \
      const u64 mk = __ballot(dmX == sV);                                        \
      int spid;                                                                  \
      if (__popcll(mk) == 1) {                                                   \
        spid = __builtin_amdgcn_readlane(__float_as_int(PX.w),                   \
                                         (int)__ffsll((long long)mk) - 1);       \
      } else {                                                                   \
        const int cand = (dmX == sV) ? __float_as_int(PX.w) : 0x7fffffff;        \
        spid = __builtin_amdgcn_readlane(imin_wave(cand), 63);                   \
      }                                                                          \
      if (lane == 63)                                                            \
        sKey[buf ^ 1][(wid << 5) | (cX >> 3)] =                                  \
            ((u64)(unsigned int)sVb << 32) | (unsigned int)(~spid);              \
      if (__float_as_int(PX.w) == spid) sCoord[cX] = PX;                         \
    }
    NEXTC(ca0) NEXTC(ca1) NEXTC(ca2) NEXTC(ca3)
    NEXTC(cb0) NEXTC(cb1) NEXTC(cb2) NEXTC(cb3)
    LOADC(ca0, Pa0, oa0) LOADC(ca1, Pa1, oa1) LOADC(ca2, Pa2, oa2) LOADC(ca3, Pa3, oa3)
    LOADC(cb0, Pb0, ob0) LOADC(cb1, Pb1, ob1) LOADC(cb2, Pb2, ob2) LOADC(cb3, Pb3, ob3)
    while (rem >= 4) {
      DIST(Pa0, oa0, dm0) DIST(Pa1, oa1, dm1) DIST(Pa2, oa2, dm2) DIST(Pa3, oa3, dm3)
      sDmin[(ca0 << 6) + lane] = dm0;
      sDmin[(ca1 << 6) + lane] = dm1;
      sDmin[(ca2 << 6) + lane] = dm2;
      sDmin[(ca3 << 6) + lane] = dm3;
      float V0 = dm0, V1 = dm1, V2 = dm2, V3 = dm3;
      fchain4(V0, V1, V2, V3);
      CHFIN(ca0, dm0, V0, Pa0)
      CHFIN(ca1, dm1, V1, Pa1)
      CHFIN(ca2, dm2, V2, Pa2)
      CHFIN(ca3, dm3, V3, Pa3)
      ca0 = cb0; Pa0 = Pb0; oa0 = ob0;
      ca1 = cb1; Pa1 = Pb1; oa1 = ob1;
      ca2 = cb2; Pa2 = Pb2; oa2 = ob2;
      ca3 = cb3; Pa3 = Pb3; oa3 = ob3;
      NEXTC(cb0) NEXTC(cb1) NEXTC(cb2) NEXTC(cb3)
      LOADC(cb0, Pb0, ob0) LOADC(cb1, Pb1, ob1) LOADC(cb2, Pb2, ob2) LOADC(cb3, Pb3, ob3)
      rem -= 4;
    }
    if (rem >= 2) {
      DIST(Pa0, oa0, dm0) DIST(Pa1, oa1, dm1)
      sDmin[(ca0 << 6) + lane] = dm0;
      sDmin[(ca1 << 6) + lane] = dm1;
      float V0 = dm0, V1 = dm1;
      fchain2(V0, V1);
      CHFIN(ca0, dm0, V0, Pa0)
      CHFIN(ca1, dm1, V1, Pa1)
      ca0 = ca2; Pa0 = Pa2; oa0 = oa2;
      rem -= 2;
    }
    if (rem >= 1) {
      DIST(Pa0, oa0, dm0)
      sDmin[(ca0 << 6) + lane] = dm0;
      float V0 = fchain(dm0);
      CHFIN(ca0, dm0, V0, Pa0)
    }
#undef NEXTC
#undef LOADC
#undef DIST
#undef CHFIN
    __syncthreads();  // the ONLY barrier per iteration
    buf ^= 1;

    // ---- C: global winner over 256 packed chunk keys (all waves, redundant) ----
    kOwn = sKey[buf][slotOwn];  // hoisted for next iteration's A (stride-1)
    const u64 k0 = sKey[buf][0 * 64 + lane];
    const u64 k1 = sKey[buf][1 * 64 + lane];
    const u64 k2 = sKey[buf][2 * 64 + lane];
    const u64 k3 = sKey[buf][3 * 64 + lane];
    double bk = fmax(fmax(__longlong_as_double((long long)k0),
                          __longlong_as_double((long long)k1)),
                     fmax(__longlong_as_double((long long)k2),
                          __longlong_as_double((long long)k3)));
    bk = kchain(bk);
    const int flo = __builtin_amdgcn_readlane(
        (int)(unsigned int)(u64)__double_as_longlong(bk), 63);
    const int fhi = __builtin_amdgcn_readlane(
        (int)(unsigned int)((u64)__double_as_longlong(bk) >> 32), 63);
    const u64 fin = ((u64)(unsigned int)fhi << 32) | (unsigned int)flo;
    const int fi = ~flo;  // winning original index (uniform)
    if (t == 0) idx_out[b * SS + it] = fi;
    // locate the winning slot (keys unique: they contain the pid)
    const u64 b0 = __ballot(k0 == fin);
    const u64 b1 = __ballot(k1 == fin);
    const u64 b2 = __ballot(k2 == fin);
    const u64 b3 = __ballot(k3 == fin);
    int slot;
    if (b0) slot = (int)__ffsll((long long)b0) - 1;
    else if (b1) slot = 64 + (int)__ffsll((long long)b1) - 1;
    else if (b2) slot = 128 + (int)__ffsll((long long)b2) - 1;
    else slot = 192 + (int)__ffsll((long long)b3) - 1;
    const int cwin = ((slot & 31) << 3) | (slot >> 5);  // un-permute slot->chunk
    const float4 W = sCoord[cwin];  // same-address broadcast ds_read_b128
    lx = W.x;
    ly = W.y;
    lz = W.z;
  }
}

// ---------------- Ball query: one wave per centroid ----------------
__global__ __launch_bounds__(256) void ballq_kernel(const float* __restrict__ pos,
                                                    const int* __restrict__ idx,
                                                    int* __restrict__ nbr,
                                                    int* __restrict__ cnt,
                                                    float* __restrict__ outC,
                                                    float* __restrict__ outB) {
  const int cs = blockIdx.x * 4 + (threadIdx.x >> 6);
  const int lane = threadIdx.x & 63;
  const int b = cs >> 12;           // S = 4096
  const int s = cs & (SS - 1);
  const float* __restrict__ p = pos + (size_t)b * NN * 3;
  const int ci = idx[cs];
  const float cx = p[ci * 3 + 0], cy = p[ci * 3 + 1], cz = p[ci * 3 + 2];
  // remove_self_loops: global src b*N+i == global dst b*S+s -> only b==0, i==s
  const int excl = (b == 0) ? s : -1;
  int count = 0;
  for (int tile = 0; tile < NN / 64; ++tile) {
    const int i = tile * 64 + lane;
    const float dx = cx - p[i * 3 + 0];
    const float dy = cy - p[i * 3 + 1];
    const float dz = cz - p[i * 3 + 2];
    const float d2 = __fadd_rn(__fadd_rn(__fmul_rn(dx, dx), __fmul_rn(dy, dy)), __fmul_rn(dz, dz));
    const bool in = (d2 <= R2C) && (i != excl);
    const unsigned long long m = __ballot(in);
    if (in) {
      const int rank = count + (int)__popcll(m & ((1ull << lane) - 1ull));
      if (rank < KK) nbr[cs * KK + rank] = i;
    }
    count += (int)__popcll(m);
    if (count >= KK) break;
  }
  if (lane == 0) {
    cnt[cs] = count < KK ? count : KK;
    outC[cs * 3 + 0] = cx;
    outC[cs * 3 + 1] = cy;
    outC[cs * 3 + 2] = cz;
    outB[cs] = (float)b;
  }
}

// ---------------- MLP + max: one block (128 thr) per centroid ----------------
#define EE 33
__global__ __launch_bounds__(128) void mlp_kernel(const float* __restrict__ x,
                                                  const float* __restrict__ pos,
                                                  const int* __restrict__ nbr,
                                                  const int* __restrict__ cnt,
                                                  const float* __restrict__ W1,
                                                  const float* __restrict__ b1,
                                                  const float* __restrict__ W2,
                                                  const float* __restrict__ b2,
                                                  const float* __restrict__ W3,
                                                  const float* __restrict__ b3,
                                                  const float* __restrict__ outC,
                                                  float* __restrict__ outX) {
  __shared__ float sF[EE][20];
  __shared__ float sH1[EE][64];
  __shared__ float sH2[EE][64];
  __shared__ int sValid[EE];

  const int cs = blockIdx.x;
  const int tid = threadIdx.x;
  const int b = cs >> 12;
  const int c = tid & 63;
  const int half = tid >> 6;

  float w1c[19], w2c[64], w3c[64];
#pragma unroll
  for (int k = 0; k < 19; ++k) w1c[k] = W1[k * 64 + c];
#pragma unroll
  for (int k = 0; k < 64; ++k) w2c[k] = W2[k * 64 + c];
#pragma unroll
  for (int k = 0; k < 64; ++k) w3c[k] = W3[k * 128 + tid];
  const float b1c = b1[c], b2c = b2[c], b3c = b3[tid];

  if (tid < EE) {
    const float ccx = outC[cs * 3 + 0], ccy = outC[cs * 3 + 1], ccz = outC[cs * 3 + 2];
    int row;
    bool valid;
    if (tid < KK) {
      const int cn = cnt[cs];
      valid = tid < cn;
      const int j = valid ? nbr[cs * KK + tid] : 0;
      row = b * NN + j;
    } else {
      // PyG add_self_loops quirk: src is flat point index dflat = b*S+s = cs
      valid = true;
      row = cs;
    }
    for (int f = 0; f < FIN; ++f) sF[tid][f] = x[(size_t)row * FIN + f];
    sF[tid][16] = pos[(size_t)row * 3 + 0] - ccx;
    sF[tid][17] = pos[(size_t)row * 3 + 1] - ccy;
    sF[tid][18] = pos[(size_t)row * 3 + 2] - ccz;
    sValid[tid] = valid ? 1 : 0;
  }
  __syncthreads();
  for (int e = half; e < EE; e += 2) {
    float acc = b1c;
#pragma unroll
    for (int k = 0; k < 19; ++k) acc += sF[e][k] * w1c[k];
    sH1[e][c] = fmaxf(acc, 0.0f);
  }
  __syncthreads();
  for (int e = half; e < EE; e += 2) {
    float acc = b2c;
#pragma unroll
    for (int k = 0; k < 64; ++k) acc += sH1[e][k] * w2c[k];
    sH2[e][c] = fmaxf(acc, 0.0f);
  }
  __syncthreads();
  float mx = -1e30f;
  for (int e = 0; e < EE; ++e) {
    if (sValid[e]) {
      float acc = b3c;
#pragma unroll
      for (int k = 0; k < 64; ++k) acc += sH2[e][k] * w3c[k];
      mx = fmaxf(mx, acc);
    }
  }
  outX[(size_t)cs * 128 + tid] = mx;
}

extern "C" void kernel_launch(void* const* d_in, const int* in_sizes, int n_in,
                              void* d_out, int out_size, void* d_ws, size_t ws_size,
                              hipStream_t stream) {
  const float* x = (const float*)d_in[0];
  const float* pos = (const float*)d_in[1];
  const float* W1 = (const float*)d_in[3];
  const float* b1 = (const float*)d_in[4];
  const float* W2 = (const float*)d_in[5];
  const float* b2 = (const float*)d_in[6];
  const float* W3 = (const float*)d_in[7];
  const float* b3 = (const float*)d_in[8];

  float* out = (float*)d_out;
  float* outX = out;                               // [B*S,128]
  float* outC = out + (size_t)BB * SS * 128;       // [B*S,3]
  float* outB = outC + (size_t)BB * SS * 3;        // [B*S]

  float4* cellpts = (float4*)d_ws;                         // BB*NN float4
  float4* bboxLo = cellpts + (size_t)BB * NN;              // BB*256
  float4* bboxHi = bboxLo + BB * NCHUNK;                   // BB*256
  int* idx = (int*)(bboxHi + BB * NCHUNK);                 // BB*SS
  int* nbr = idx + BB * SS;                                // BB*SS*KK
  int* cnt = nbr + (size_t)BB * SS * KK;                   // BB*SS

  hipLaunchKernelGGL(bin_kernel, dim3(BB), dim3(512), 0, stream, pos, cellpts, bboxLo, bboxHi);
  hipLaunchKernelGGL(fps_kernel, dim3(BB), dim3(512), 0, stream, pos, cellpts, bboxLo, bboxHi, idx);
  hipLaunchKernelGGL(ballq_kernel, dim3(BB * SS / 4), dim3(256), 0, stream,
                     pos, idx, nbr, cnt, outC, outB);
  hipLaunchKernelGGL(mlp_kernel, dim3(BB * SS), dim3(128), 0, stream,
                     x, pos, nbr, cnt, W1, b1, W2, b2, W3, b3, outC, outX);
}

// Round 14
// 4998.898 us; speedup vs baseline: 1.3299x; 1.3299x over previous
//
#include <hip/hip_runtime.h>
#include <cstdint>
#include <cstddef>

#define BB 2
#define NN 16384
#define SS 4096
#define KK 32
#define FIN 16
#define R2C 0.01f
#define NCHUNK 256   // chunks = 64-slot ranges of the Morton-cell-sorted point array

typedef unsigned long long u64;

// ---------------- f64-packed-key DPP wave max (result valid at lane 63) -------
// key_u64 = (float_bits(dmin) << 32) | ~pid. dmin >= 0 => high bit 0 => as a
// double the key is positive and finite, so f64 ordering == u64 ordering and
// one v_max_f64 replaces cmp+cndmask. Tie -> lowest original index via ~pid.
// update_dpp(old=own, src=own): invalid lanes keep own value -> idempotent max.
__device__ __forceinline__ double pack_key(float dm, int pidbits) {
  const u64 k = ((u64)(unsigned int)__float_as_int(dm) << 32) |
                (unsigned int)(~pidbits);
  return __longlong_as_double((long long)k);
}
template <int CTRL>
__device__ __forceinline__ double kstep(double k) {
  const u64 kb = (u64)__double_as_longlong(k);
  const int lo = (int)(unsigned int)kb;
  const int hi = (int)(unsigned int)(kb >> 32);
  const int nlo = __builtin_amdgcn_update_dpp(lo, lo, CTRL, 0xf, 0xf, false);
  const int nhi = __builtin_amdgcn_update_dpp(hi, hi, CTRL, 0xf, 0xf, false);
  const double nk = __longlong_as_double(
      (long long)(((u64)(unsigned int)nhi << 32) | (unsigned int)nlo));
  return fmax(k, nk);
}
__device__ __forceinline__ double kchain(double k) {
  k = kstep<0x111>(k);  // row_shr:1
  k = kstep<0x112>(k);  // row_shr:2
  k = kstep<0x114>(k);  // row_shr:4
  k = kstep<0x118>(k);  // row_shr:8
  k = kstep<0x142>(k);  // row_bcast15
  k = kstep<0x143>(k);  // row_bcast31
  return k;             // lane 63 holds the wave max
}
template <int CTRL>
__device__ __forceinline__ void kstep2(double& a, double& b) {
  a = kstep<CTRL>(a);
  b = kstep<CTRL>(b);
}
__device__ __forceinline__ void kchain2(double& a, double& b) {
  kstep2<0x111>(a, b);
  kstep2<0x112>(a, b);
  kstep2<0x114>(a, b);
  kstep2<0x118>(a, b);
  kstep2<0x142>(a, b);
  kstep2<0x143>(a, b);
}
template <int CTRL>
__device__ __forceinline__ void kstep4(double& a, double& b, double& c, double& d) {
  a = kstep<CTRL>(a);
  b = kstep<CTRL>(b);
  c = kstep<CTRL>(c);
  d = kstep<CTRL>(d);
}
__device__ __forceinline__ void kchain4(double& a, double& b, double& c, double& d) {
  kstep4<0x111>(a, b, c, d);
  kstep4<0x112>(a, b, c, d);
  kstep4<0x114>(a, b, c, d);
  kstep4<0x118>(a, b, c, d);
  kstep4<0x142>(a, b, c, d);
  kstep4<0x143>(a, b, c, d);
}

// ---------------- binning: counting-sort points into Morton-ordered cells ----------------
__device__ __forceinline__ int part3(int x) {  // 3 bits -> bits 0,3,6
  return (x & 1) | ((x & 2) << 2) | ((x & 4) << 4);
}

__global__ __launch_bounds__(512) void bin_kernel(const float* __restrict__ pos,
                                                  float4* __restrict__ cellpts,
                                                  float4* __restrict__ bboxLo,
                                                  float4* __restrict__ bboxHi) {
  const int b = blockIdx.x, t = threadIdx.x;
  const float* __restrict__ p = pos + (size_t)b * NN * 3;
  __shared__ int hist[512], sA[512], sB[512];
  hist[t] = 0;
  __syncthreads();
  int cidc[NN / 512];  // 32 per thread
#pragma unroll
  for (int m = 0; m < NN / 512; ++m) {
    const int i = m * 512 + t;
    const float x = p[i * 3 + 0], y = p[i * 3 + 1], z = p[i * 3 + 2];
    const int cx = min(7, (int)(x * 8.0f));
    const int cy = min(7, (int)(y * 8.0f));
    const int cz = min(7, (int)(z * 8.0f));
    const int cid = part3(cx) | (part3(cy) << 1) | (part3(cz) << 2);  // Morton
    cidc[m] = cid;
    atomicAdd(&hist[cid], 1);
  }
  __syncthreads();
  sA[t] = hist[t];
  __syncthreads();
  int* src = sA;
  int* dst = sB;
  for (int off = 1; off < 512; off <<= 1) {
    int v = src[t];
    if (t >= off) v += src[t - off];
    dst[t] = v;
    __syncthreads();
    int* tmp = src; src = dst; dst = tmp;
  }
  const int excl = (t == 0) ? 0 : src[t - 1];
  __syncthreads();
  hist[t] = excl;
  __syncthreads();
#pragma unroll
  for (int m = 0; m < NN / 512; ++m) {
    const int i = m * 512 + t;
    const int slot = atomicAdd(&hist[cidc[m]], 1);
    cellpts[(size_t)b * NN + slot] =
        make_float4(p[i * 3 + 0], p[i * 3 + 1], p[i * 3 + 2], __int_as_float(i));
  }
  __threadfence_block();
  __syncthreads();
  if (t < NCHUNK) {
    float4 lo = make_float4(1e30f, 1e30f, 1e30f, 0.0f);
    float4 hi = make_float4(-1e30f, -1e30f, -1e30f, 0.0f);
    for (int k = 0; k < 64; ++k) {
      const float4 q = cellpts[(size_t)b * NN + t * 64 + k];
      lo.x = fminf(lo.x, q.x); lo.y = fminf(lo.y, q.y); lo.z = fminf(lo.z, q.z);
      hi.x = fmaxf(hi.x, q.x); hi.y = fmaxf(hi.y, q.y); hi.z = fmaxf(hi.z, q.z);
    }
    bboxLo[b * NCHUNK + t] = lo;
    bboxHi[b * NCHUNK + t] = hi;
  }
}

// ---------------- FPS: one 1024-thread block (16 waves) per batch ----------------
// Exact AABB-pruned FPS (bit-identical, proven r5-r11). r14 = r11 structure
// (best measured: fps 4.96 ms) with 16 waves instead of 8: the straggler
// wave's B chunk count halves. Chunk c owned by wave (c & 15); key slot
// (wid<<4)|(c>>4) keeps owner access stride-1 (no bank conflicts). Quads of
// chunks with four interleaved f64-key DPP chains; one barrier per iteration.
#define FPS_T 1024
#define FPS_NW 16

__global__ __launch_bounds__(FPS_T, 1) void fps_kernel(const float* __restrict__ pos,
                                                       const float4* __restrict__ cellpts,
                                                       const float4* __restrict__ bboxLo,
                                                       const float4* __restrict__ bboxHi,
                                                       int* __restrict__ idx_out) {
  const int b = blockIdx.x;
  const int t = threadIdx.x;
  const int wid = t >> 6;   // 0..15
  const int lane = t & 63;
  const float* __restrict__ p = pos + (size_t)b * NN * 3;
  const float4* __restrict__ cp = cellpts + (size_t)b * NN;

  __shared__ float sDmin[NN];      // 64 KB, indexed by sorted slot
  __shared__ u64 sKey[2][NCHUNK];  // double-buffered packed chunk maxima (4 KB)

  const int cown = ((lane & 15) << 4) | wid;  // owned chunk (real for lane<16)
  const int slotOwn = (wid << 4) | (lane & 15);
  const float4 blo = bboxLo[b * NCHUNK + cown];
  const float4 bhi = bboxHi[b * NCHUNK + cown];

  const u64 initKey = (u64)__double_as_longlong(pack_key(1e30f, 0));
  if (t < NCHUNK) sKey[0][t] = initKey;
  for (int s = t; s < NN; s += FPS_T) sDmin[s] = 1e10f;
  if (t == 0) idx_out[b * SS + 0] = 0;
  float lx = p[0], ly = p[1], lz = p[2];
  u64 kOwn = initKey;  // sKey[buf][slotOwn], carried across iterations
  __syncthreads();

  int buf = 0;

  for (int it = 1; it < SS; ++it) {
    // ---- A: test owned chunks (pure VALU, boxes in regs) ----
    const float mvOwn = __int_as_float((int)(unsigned int)(kOwn >> 32));
    const float ax = fmaxf(fmaxf(blo.x - lx, lx - bhi.x), 0.0f);
    const float ay = fmaxf(fmaxf(blo.y - ly, ly - bhi.y), 0.0f);
    const float az = fmaxf(fmaxf(blo.z - lz, lz - bhi.z), 0.0f);
    const float bl2 = ax * ax + ay * ay + az * az;
    // skip iff conservative lower bound exceeds chunk max dmin: then
    // min(dmin_j, d_j) == dmin_j exactly for every member (bit-exact skip).
    const bool act = (lane < 16) && !(bl2 * 0.99999f > mvOwn);
    if ((lane < 16) && !act) sKey[buf ^ 1][slotOwn] = kOwn;  // carry (stride-1)
    unsigned int mm = (unsigned int)__ballot(act);  // wave-uniform, low 16 bits

    // ---- B: quads of chunks, 8-deep register prefetch ----
    int ca0 = -1, ca1 = -1, ca2 = -1, ca3 = -1;
    int cb0 = -1, cb1 = -1, cb2 = -1, cb3 = -1;
    float4 Pa0, Pa1, Pa2, Pa3, Pb0, Pb1, Pb2, Pb3;
    float oa0 = 0, oa1 = 0, oa2 = 0, oa3 = 0, ob0 = 0, ob1 = 0, ob2 = 0, ob3 = 0;
#define POPC(cX, PX, oX)                                  \
    if (mm) {                                             \
      const int l = (int)__builtin_ctz(mm); mm &= mm - 1; \
      cX = (l << 4) | wid;                                \
      PX = cp[(size_t)((cX << 6) + lane)];                \
      oX = sDmin[(cX << 6) + lane];                       \
    }
#define DIST(PX, oX, dmX)                                                        \
    {                                                                            \
      const float dx = PX.x - lx, dy = PX.y - ly, dz = PX.z - lz;                \
      const float d = __fadd_rn(__fadd_rn(__fmul_rn(dx, dx), __fmul_rn(dy, dy)), \
                                __fmul_rn(dz, dz));                              \
      dmX = fminf(oX, d);                                                        \
    }
    POPC(ca0, Pa0, oa0) POPC(ca1, Pa1, oa1) POPC(ca2, Pa2, oa2) POPC(ca3, Pa3, oa3)
    POPC(cb0, Pb0, ob0) POPC(cb1, Pb1, ob1) POPC(cb2, Pb2, ob2) POPC(cb3, Pb3, ob3)

    while (ca3 >= 0) {  // >=4 available: full quad (wave-uniform condition)
      float dm0, dm1, dm2, dm3;
      DIST(Pa0, oa0, dm0) DIST(Pa1, oa1, dm1) DIST(Pa2, oa2, dm2) DIST(Pa3, oa3, dm3)
      sDmin[(ca0 << 6) + lane] = dm0;
      sDmin[(ca1 << 6) + lane] = dm1;
      sDmin[(ca2 << 6) + lane] = dm2;
      sDmin[(ca3 << 6) + lane] = dm3;
      double k0 = pack_key(dm0, __float_as_int(Pa0.w));
      double k1 = pack_key(dm1, __float_as_int(Pa1.w));
      double k2 = pack_key(dm2, __float_as_int(Pa2.w));
      double k3 = pack_key(dm3, __float_as_int(Pa3.w));
      kchain4(k0, k1, k2, k3);
      if (lane == 63) {
        sKey[buf ^ 1][(wid << 4) | (ca0 >> 4)] = (u64)__double_as_longlong(k0);
        sKey[buf ^ 1][(wid << 4) | (ca1 >> 4)] = (u64)__double_as_longlong(k1);
        sKey[buf ^ 1][(wid << 4) | (ca2 >> 4)] = (u64)__double_as_longlong(k2);
        sKey[buf ^ 1][(wid << 4) | (ca3 >> 4)] = (u64)__double_as_longlong(k3);
      }
      ca0 = cb0; Pa0 = Pb0; oa0 = ob0;
      ca1 = cb1; Pa1 = Pb1; oa1 = ob1;
      ca2 = cb2; Pa2 = Pb2; oa2 = ob2;
      ca3 = cb3; Pa3 = Pb3; oa3 = ob3;
      cb0 = -1; cb1 = -1; cb2 = -1; cb3 = -1;
      POPC(cb0, Pb0, ob0) POPC(cb1, Pb1, ob1) POPC(cb2, Pb2, ob2) POPC(cb3, Pb3, ob3)
    }
    // tail: 0-3 chunks left in ca0..ca2 (wave-uniform branches)
    if (ca1 >= 0) {  // pair
      float dm0, dm1;
      DIST(Pa0, oa0, dm0) DIST(Pa1, oa1, dm1)
      sDmin[(ca0 << 6) + lane] = dm0;
      sDmin[(ca1 << 6) + lane] = dm1;
      double k0 = pack_key(dm0, __float_as_int(Pa0.w));
      double k1 = pack_key(dm1, __float_as_int(Pa1.w));
      kchain2(k0, k1);
      if (lane == 63) {
        sKey[buf ^ 1][(wid << 4) | (ca0 >> 4)] = (u64)__double_as_longlong(k0);
        sKey[buf ^ 1][(wid << 4) | (ca1 >> 4)] = (u64)__double_as_longlong(k1);
      }
      ca0 = ca2; Pa0 = Pa2; oa0 = oa2;
    }
    if (ca0 >= 0) {  // single
      float dm0;
      DIST(Pa0, oa0, dm0)
      sDmin[(ca0 << 6) + lane] = dm0;
      double k0 = pack_key(dm0, __float_as_int(Pa0.w));
      k0 = kchain(k0);
      if (lane == 63)
        sKey[buf ^ 1][(wid << 4) | (ca0 >> 4)] = (u64)__double_as_longlong(k0);
    }
#undef POPC
#undef DIST
    __syncthreads();  // the ONLY barrier per iteration
    buf ^= 1;

    // ---- C: global winner over 256 packed chunk keys (all waves, redundant) ----
    kOwn = sKey[buf][slotOwn];  // hoisted for next iteration's A (stride-1)
    double bk = 0.0;            // all keys are positive doubles
#pragma unroll
    for (int g = 0; g < 4; ++g) {
      const double k = __longlong_as_double((long long)sKey[buf][g * 64 + lane]);
      bk = fmax(bk, k);
    }
    bk = kchain(bk);
    const int lo63 = __builtin_amdgcn_readlane(
        (int)(unsigned int)(u64)__double_as_longlong(bk), 63);
    const int fi = ~lo63;  // unpack winning original index (uniform)
    if (t == 0) idx_out[b * SS + it] = fi;
    // uniform (scalar) loads of winner coords
    lx = p[fi * 3 + 0];
    ly = p[fi * 3 + 1];
    lz = p[fi * 3 + 2];
  }
}

// ---------------- Ball query: one wave per centroid ----------------
__global__ __launch_bounds__(256) void ballq_kernel(const float* __restrict__ pos,
                                                    const int* __restrict__ idx,
                                                    int* __restrict__ nbr,
                                                    int* __restrict__ cnt,
                                                    float* __restrict__ outC,
                                                    float* __restrict__ outB) {
  const int cs = blockIdx.x * 4 + (threadIdx.x >> 6);
  const int lane = threadIdx.x & 63;
  const int b = cs >> 12;           // S = 4096
  const int s = cs & (SS - 1);
  const float* __restrict__ p = pos + (size_t)b * NN * 3;
  const int ci = idx[cs];
  const float cx = p[ci * 3 + 0], cy = p[ci * 3 + 1], cz = p[ci * 3 + 2];
  // remove_self_loops: global src b*N+i == global dst b*S+s -> only b==0, i==s
  const int excl = (b == 0) ? s : -1;
  int count = 0;
  for (int tile = 0; tile < NN / 64; ++tile) {
    const int i = tile * 64 + lane;
    const float dx = cx - p[i * 3 + 0];
    const float dy = cy - p[i * 3 + 1];
    const float dz = cz - p[i * 3 + 2];
    const float d2 = __fadd_rn(__fadd_rn(__fmul_rn(dx, dx), __fmul_rn(dy, dy)), __fmul_rn(dz, dz));
    const bool in = (d2 <= R2C) && (i != excl);
    const unsigned long long m = __ballot(in);
    if (in) {
      const int rank = count + (int)__popcll(m & ((1ull << lane) - 1ull));
      if (rank < KK) nbr[cs * KK + rank] = i;
    }
    count += (int)__popcll(m);
    if (count >= KK) break;
  }
  if (lane == 0) {
    cnt[cs] = count < KK ? count : KK;
    outC[cs * 3 + 0] = cx;
    outC[cs * 3 + 1] = cy;
    outC[cs * 3 + 2] = cz;
    outB[cs] = (float)b;
  }
}

// ---------------- MLP + max: one block (128 thr) per centroid ----------------
#define EE 33
__global__ __launch_bounds__(128) void mlp_kernel(const float* __restrict__ x,
                                                  const float* __restrict__ pos,
                                                  const int* __restrict__ nbr,
                                                  const int* __restrict__ cnt,
                                                  const float* __restrict__ W1,
                                                  const float* __restrict__ b1,
                                                  const float* __restrict__ W2,
                                                  const float* __restrict__ b2,
                                                  const float* __restrict__ W3,
                                                  const float* __restrict__ b3,
                                                  const float* __restrict__ outC,
                                                  float* __restrict__ outX) {
  __shared__ float sF[EE][20];
  __shared__ float sH1[EE][64];
  __shared__ float sH2[EE][64];
  __shared__ int sValid[EE];

  const int cs = blockIdx.x;
  const int tid = threadIdx.x;
  const int b = cs >> 12;
  const int c = tid & 63;
  const int half = tid >> 6;

  float w1c[19], w2c[64], w3c[64];
#pragma unroll
  for (int k = 0; k < 19; ++k) w1c[k] = W1[k * 64 + c];
#pragma unroll
  for (int k = 0; k < 64; ++k) w2c[k] = W2[k * 64 + c];
#pragma unroll
  for (int k = 0; k < 64; ++k) w3c[k] = W3[k * 128 + tid];
  const float b1c = b1[c], b2c = b2[c], b3c = b3[tid];

  if (tid < EE) {
    const float ccx = outC[cs * 3 + 0], ccy = outC[cs * 3 + 1], ccz = outC[cs * 3 + 2];
    int row;
    bool valid;
    if (tid < KK) {
      const int cn = cnt[cs];
      valid = tid < cn;
      const int j = valid ? nbr[cs * KK + tid] : 0;
      row = b * NN + j;
    } else {
      // PyG add_self_loops quirk: src is flat point index dflat = b*S+s = cs
      valid = true;
      row = cs;
    }
    for (int f = 0; f < FIN; ++f) sF[tid][f] = x[(size_t)row * FIN + f];
    sF[tid][16] = pos[(size_t)row * 3 + 0] - ccx;
    sF[tid][17] = pos[(size_t)row * 3 + 1] - ccy;
    sF[tid][18] = pos[(size_t)row * 3 + 2] - ccz;
    sValid[tid] = valid ? 1 : 0;
  }
  __syncthreads();
  for (int e = half; e < EE; e += 2) {
    float acc = b1c;
#pragma unroll
    for (int k = 0; k < 19; ++k) acc += sF[e][k] * w1c[k];
    sH1[e][c] = fmaxf(acc, 0.0f);
  }
  __syncthreads();
  for (int e = half; e < EE; e += 2) {
    float acc = b2c;
#pragma unroll
    for (int k = 0; k < 64; ++k) acc += sH1[e][k] * w2c[k];
    sH2[e][c] = fmaxf(acc, 0.0f);
  }
  __syncthreads();
  float mx = -1e30f;
  for (int e = 0; e < EE; ++e) {
    if (sValid[e]) {
      float acc = b3c;
#pragma unroll
      for (int k = 0; k < 64; ++k) acc += sH2[e][k] * w3c[k];
      mx = fmaxf(mx, acc);
    }
  }
  outX[(size_t)cs * 128 + tid] = mx;
}

extern "C" void kernel_launch(void* const* d_in, const int* in_sizes, int n_in,
                              void* d_out, int out_size, void* d_ws, size_t ws_size,
                              hipStream_t stream) {
  const float* x = (const float*)d_in[0];
  const float* pos = (const float*)d_in[1];
  const float* W1 = (const float*)d_in[3];
  const float* b1 = (const float*)d_in[4];
  const float* W2 = (const float*)d_in[5];
  const float* b2 = (const float*)d_in[6];
  const float* W3 = (const float*)d_in[7];
  const float* b3 = (const float*)d_in[8];

  float* out = (float*)d_out;
  float* outX = out;                               // [B*S,128]
  float* outC = out + (size_t)BB * SS * 128;       // [B*S,3]
  float* outB = outC + (size_t)BB * SS * 3;        // [B*S]

  float4* cellpts = (float4*)d_ws;                         // BB*NN float4
  float4* bboxLo = cellpts + (size_t)BB * NN;              // BB*256
  float4* bboxHi = bboxLo + BB * NCHUNK;                   // BB*256
  int* idx = (int*)(bboxHi + BB * NCHUNK);                 // BB*SS
  int* nbr = idx + BB * SS;                                // BB*SS*KK
  int* cnt = nbr + (size_t)BB * SS * KK;                   // BB*SS

  hipLaunchKernelGGL(bin_kernel, dim3(BB), dim3(512), 0, stream, pos, cellpts, bboxLo, bboxHi);
  hipLaunchKernelGGL(fps_kernel, dim3(BB), dim3(FPS_T), 0, stream, pos, cellpts, bboxLo, bboxHi, idx);
  hipLaunchKernelGGL(ballq_kernel, dim3(BB * SS / 4), dim3(256), 0, stream,
                     pos, idx, nbr, cnt, outC, outB);
  hipLaunchKernelGGL(mlp_kernel, dim3(BB * SS), dim3(128), 0, stream,
                     x, pos, nbr, cnt, W1, b1, W2, b2, W3, b3, outC, outX);
}